// Round 5
// baseline (761.170 us; speedup 1.0000x reference)
//
#include <hip/hip_runtime.h>
#include <cstddef>
#include <cstdint>

// Shapes fixed by reference setup_inputs():
#define T_LEN 2048
#define B_SZ  32
#define D_SZ  512
#define BD    (B_SZ * D_SZ)   // 16384

// ---------------------------------------------------------------------------
// GEMM: per output element, single sequential fmaf chain over k=0..511
// ascending, then + bias[e]. Chain order (k0 asc, kq asc, x/y/z/w asc)
// identical to the bit-exact-verified baseline.
//
// R5: LDS-pipe relief (R4 analysis: LDS demand 3072 cyc/CU per 2048-cyc
// VALU wall -> LDS-bound, not FMA-bound).
//  - BOTH A and B staged via global_load_lds into linear [2][128*16] tiles
//    (32 KB total). No ds_write instructions at all; no prefetch registers.
//  - XOR quad swizzles (linear dest + inverse-swizzled SOURCE + same XOR on
//    READ, rule #21):
//      A: p = q ^ (row&3)      -> wave's 4 A-rows (ty&3 distinct) hit
//                                 disjoint bank-quads: 0-way conflict.
//      B: p = q ^ ((row>>1)&3) -> 16 rows map 2 rows/start-bank: 2-way,
//                                 free (m136), same as padded layout.
//    Read offsets: aq=(kq^(ty&3))<<2, bq=(kq^((tx>>1)&3))<<2 -- kq is
//    unroll-constant, XOR masks loop-invariant -> base+imm addressing.
//  - ONE barrier per 16-wide K-chunk; glds for chunk k+1 issued before
//    compute of chunk k, drained by the barrier.
//  - Bijective XCD swizzle kept (proven: FETCH 272->86 MB).
// NOTE: plain __launch_bounds__(256). (256,4) clamped to 64 VGPR and
// spilled acc[8][8] (8.5x regression). Do not re-add.
// ---------------------------------------------------------------------------
#define BM   128
#define BN   128

typedef const __attribute__((address_space(1))) uint32_t* gas1_t;
typedef __attribute__((address_space(3))) uint32_t* las3_t;

__global__ __launch_bounds__(256) void gemm8x8_kernel(
    const float* __restrict__ A,     // [rows, 512]
    const float* __restrict__ W,     // [512, 512]
    const float* __restrict__ bias,  // [512]
    float* __restrict__ Y)           // [rows, 512]
{
#pragma clang fp contract(off)
  __shared__ float As[2][BM * 16];     // 8 KB per buf, linear, glds dest
  __shared__ float Bs[2][BN * 16];     // 8 KB per buf, linear, glds dest

  const int tid = threadIdx.x;
  const int tx  = tid & 15;          // n-lane: n = tx + 16*j
  const int ty  = tid >> 4;          // m-lane: m = ty + 16*i (0..15)
  const int cA  = ty & 3;            // A read-side quad XOR
  const int cB  = (tx >> 1) & 3;     // B read-side quad XOR

  // Bijective XCD swizzle (n-fast): 4 n-tiles sharing an A-panel land on
  // the same XCD's L2 adjacently in time.
  const int nwg  = (int)(gridDim.x * gridDim.y);
  const int orig = (int)(blockIdx.y * gridDim.x + blockIdx.x);
  const int q    = nwg >> 3, r = nwg & 7;
  const int xcd  = orig & 7, loc = orig >> 3;
  const int tix  = (xcd < r ? xcd * (q + 1) : r * (q + 1) + (xcd - r) * q) + loc;
  const int m0   = (tix >> 2) * BM;   // gridDim.y == 4 (D_SZ/BN)
  const int n0   = (tix & 3) * BN;

  // glds staging: per chunk, A tile = 8 segs of 1 KB (16 rows each), B same.
  // Wave w stages A segs {2w,2w+1} and B segs {2w,2w+1}.
  // Lane l lands at seg_base + l*16B -> phys row rloc=l>>2, phys quad l&3.
  // Lane must FETCH the logical quad that belongs at its phys slot:
  //   A: qlogA = (l&3) ^ (rloc&3);   B: qlogB = (l&3) ^ ((rloc>>1)&3)
  // (seg index contributes 0 mod 4 to row&3 and (row>>1)&3.)
  const int lane  = tid & 63;
  const int wid   = tid >> 6;                      // 0..3
  const int rloc  = lane >> 2;
  const int qA4   = (((lane & 3) ^ (rloc & 3)) << 2);
  const int qB4   = (((lane & 3) ^ ((rloc >> 1) & 3)) << 2);
  const int s0    = 2 * wid, s1 = 2 * wid + 1;
  const int oS0   = s0 * 256, oS1 = s1 * 256;      // LDS float offsets
  const float* gA0 = A + (size_t)(m0 + s0 * 16 + rloc) * D_SZ + qA4;
  const float* gA1 = A + (size_t)(m0 + s1 * 16 + rloc) * D_SZ + qA4;
  const float* gB0 = W + (size_t)(n0 + s0 * 16 + rloc) * D_SZ + qB4;
  const float* gB1 = W + (size_t)(n0 + s1 * 16 + rloc) * D_SZ + qB4;

#define STAGE(BUF, KOFF)                                                      \
  do {                                                                        \
    __builtin_amdgcn_global_load_lds((gas1_t)(const void*)(gA0 + (KOFF)),     \
                                     (las3_t)(void*)(&As[BUF][oS0]), 16, 0, 0);\
    __builtin_amdgcn_global_load_lds((gas1_t)(const void*)(gA1 + (KOFF)),     \
                                     (las3_t)(void*)(&As[BUF][oS1]), 16, 0, 0);\
    __builtin_amdgcn_global_load_lds((gas1_t)(const void*)(gB0 + (KOFF)),     \
                                     (las3_t)(void*)(&Bs[BUF][oS0]), 16, 0, 0);\
    __builtin_amdgcn_global_load_lds((gas1_t)(const void*)(gB1 + (KOFF)),     \
                                     (las3_t)(void*)(&Bs[BUF][oS1]), 16, 0, 0);\
  } while (0)

  float acc[8][8];
#pragma unroll
  for (int i = 0; i < 8; ++i)
#pragma unroll
    for (int j = 0; j < 8; ++j) acc[i][j] = 0.0f;

  STAGE(0, 0);
  __syncthreads();

#pragma unroll 1
  for (int kc = 0; kc < 32; ++kc) {
    const int cur = kc & 1;
    if (kc + 1 < 32) STAGE(cur ^ 1, (kc + 1) * 16);

    const float* asb = &As[cur][0];
    const float* bsb = &Bs[cur][0];
#pragma unroll
    for (int kq = 0; kq < 4; ++kq) {
      const int bq = ((kq ^ cB) & 3) << 2;   // phys quad holding logical kq
      const int aq = ((kq ^ cA) & 3) << 2;
      float4 bfr[8];
#pragma unroll
      for (int j = 0; j < 8; ++j)
        bfr[j] = *(const float4*)&bsb[(tx + 16 * j) * 16 + bq];
#pragma unroll
      for (int i = 0; i < 8; ++i) {
        const float4 a = *(const float4*)&asb[(ty + 16 * i) * 16 + aq];
#pragma unroll
        for (int j = 0; j < 8; ++j) {
          acc[i][j] = fmaf(a.x, bfr[j].x, acc[i][j]);
          acc[i][j] = fmaf(a.y, bfr[j].y, acc[i][j]);
          acc[i][j] = fmaf(a.z, bfr[j].z, acc[i][j]);
          acc[i][j] = fmaf(a.w, bfr[j].w, acc[i][j]);
        }
      }
    }
    __syncthreads();   // drains vmcnt: next buf landed; cur reads complete.
  }
#undef STAGE

#pragma unroll
  for (int i = 0; i < 8; ++i) {
    const int m = m0 + ty + 16 * i;
#pragma unroll
    for (int j = 0; j < 8; ++j) {
      const int n = n0 + tx + 16 * j;
      Y[(size_t)m * D_SZ + n] = acc[i][j] + bias[n];
    }
  }
}

// ---------------------------------------------------------------------------
// Chunked LIF scan with warm-up, writing out directly.
// T split into CHK=8 chunks of CLEN=256. Per thread: 64-step warm-up from
// v=0 over the neighbor chunk (residual influence 2^-64 << ulp; any spike
// resets to exact 0 -> bit-exact merge), then 256 real steps per direction.
// R5: ca/cb register double-buffer restored (R4 regression: shared creg
// serialized each 32-load batch behind the previous dependent chain).
// Step math identical to verified scan: v += (c-v)*0.5; s = (v-1)>=0; reset.
// ---------------------------------------------------------------------------
#define CHK   8
#define CLEN  256

__global__ __launch_bounds__(64) void scan_chunk_kernel(
    const float* __restrict__ Y,
    float* __restrict__ out)
{
#pragma clang fp contract(off)
  const int idx = blockIdx.x * 64 + threadIdx.x;   // column in [0, BD)
  const int c   = blockIdx.y;                      // chunk
  const int t0  = c * CLEN;
  float ca[32], cb[32];
  uint32_t sf0, sf1, sf2, sf3, sf4, sf5, sf6, sf7;
  float v;

#define LD(R, TB)                                                             \
  _Pragma("unroll")                                                           \
  for (int j = 0; j < 32; ++j) R[j] = Y[(size_t)((TB) + j) * BD + idx];

#define FCH(R, WREC)                                                          \
  {                                                                           \
    uint32_t w_ = 0;                                                          \
    _Pragma("unroll")                                                         \
    for (int j = 0; j < 32; ++j) {                                            \
      v = v + (R[j] - v) * 0.5f;                                              \
      const bool s = (v - 1.0f) >= 0.0f;                                      \
      w_ |= (uint32_t)s << j;                                                 \
      v = s ? 0.0f : v;                                                       \
    }                                                                         \
    WREC;                                                                     \
  }

#define BCH(R, WREC)                                                          \
  {                                                                           \
    uint32_t w_ = 0;                                                          \
    _Pragma("unroll")                                                         \
    for (int j = 31; j >= 0; --j) {                                           \
      v = v + (R[j] - v) * 0.5f;                                              \
      const bool s = (v - 1.0f) >= 0.0f;                                      \
      w_ |= (uint32_t)s << j;                                                 \
      v = s ? 0.0f : v;                                                       \
    }                                                                         \
    WREC;                                                                     \
  }

  // Write group G combining stored fwd word SF with just-computed bwd w_.
#define WOUT(SF, G)                                                           \
  _Pragma("unroll")                                                           \
  for (int j = 0; j < 32; ++j)                                                \
    out[(size_t)(t0 + (G) * 32 + j) * BD + idx] =                             \
        (float)(((SF >> j) & 1u) + ((w_ >> j) & 1u));

  // ---------------- forward (t ascending) ----------------
  v = 0.0f;
  if (c > 0) {                       // warm-up: 64 steps over previous chunk
    LD(ca, t0 - 64)
    LD(cb, t0 - 32)
    FCH(ca, (void)0)
    LD(ca, t0)                       // real group 0 prefetched under chain
    FCH(cb, (void)0)
  } else {
    LD(ca, t0)
  }
  LD(cb, t0 + 32)  FCH(ca, sf0 = w_)
  LD(ca, t0 + 64)  FCH(cb, sf1 = w_)
  LD(cb, t0 + 96)  FCH(ca, sf2 = w_)
  LD(ca, t0 + 128) FCH(cb, sf3 = w_)
  LD(cb, t0 + 160) FCH(ca, sf4 = w_)
  LD(ca, t0 + 192) FCH(cb, sf5 = w_)
  LD(cb, t0 + 224) FCH(ca, sf6 = w_)
                   FCH(cb, sf7 = w_)

  // ---------------- backward (t descending) ----------------
  v = 0.0f;
  if (c < CHK - 1) {                 // warm-up: 64 steps over next chunk
    LD(ca, t0 + CLEN + 32)
    LD(cb, t0 + CLEN)
    BCH(ca, (void)0)
    LD(ca, t0 + 224)                 // real group 7 prefetched under chain
    BCH(cb, (void)0)
  } else {
    LD(ca, t0 + 224)
  }
  LD(cb, t0 + 192) BCH(ca, WOUT(sf7, 7))
  LD(ca, t0 + 160) BCH(cb, WOUT(sf6, 6))
  LD(cb, t0 + 128) BCH(ca, WOUT(sf5, 5))
  LD(ca, t0 + 96)  BCH(cb, WOUT(sf4, 4))
  LD(cb, t0 + 64)  BCH(ca, WOUT(sf3, 3))
  LD(ca, t0 + 32)  BCH(cb, WOUT(sf2, 2))
  LD(cb, t0)       BCH(ca, WOUT(sf1, 1))
                   BCH(cb, WOUT(sf0, 0))

#undef LD
#undef FCH
#undef BCH
#undef WOUT
}

// ---------------------------------------------------------------------------
// Fallback scans (used only if ws is too small for full Y).
// ---------------------------------------------------------------------------
__global__ __launch_bounds__(64) void lif_fwd_kernel(
    const float* __restrict__ Y, float* __restrict__ out,
    int tlen, float* __restrict__ vstate, int carry)
{
#pragma clang fp contract(off)
  const int idx = blockIdx.x * 64 + threadIdx.x;
  float v = carry ? vstate[idx] : 0.0f;
#pragma unroll 16
  for (int t = 0; t < tlen; ++t) {
    const float c = Y[(size_t)t * BD + idx];
    v = v + (c - v) * 0.5f;
    const bool s = (v - 1.0f) >= 0.0f;
    out[(size_t)t * BD + idx] = s ? 1.0f : 0.0f;
    v = s ? 0.0f : v;
  }
  vstate[idx] = v;
}

__global__ __launch_bounds__(64) void lif_bwd_kernel(
    const float* __restrict__ Y, float* __restrict__ out,
    int tlen, float* __restrict__ vstate, int carry)
{
#pragma clang fp contract(off)
  const int idx = blockIdx.x * 64 + threadIdx.x;
  float v = carry ? vstate[idx] : 0.0f;
#pragma unroll 16
  for (int tt = 0; tt < tlen; ++tt) {
    const size_t t = (size_t)(tlen - 1 - tt);
    const float c = Y[t * BD + idx];
    v = v + (c - v) * 0.5f;
    const bool s = (v - 1.0f) >= 0.0f;
    out[t * BD + idx] += s ? 1.0f : 0.0f;
    v = s ? 0.0f : v;
  }
  vstate[idx] = v;
}

// ---------------------------------------------------------------------------
extern "C" void kernel_launch(void* const* d_in, const int* in_sizes, int n_in,
                              void* d_out, int out_size, void* d_ws, size_t ws_size,
                              hipStream_t stream)
{
  const float* x = (const float*)d_in[0];   // [T, B, D]
  const float* W = (const float*)d_in[1];   // [D, D]
  const float* b = (const float*)d_in[2];   // [D]
  float* out = (float*)d_out;               // [T, B, D]

  const size_t full_bytes = (size_t)T_LEN * BD * sizeof(float);     // 134 MB
  const size_t vbytes     = (size_t)BD * sizeof(float);

  if (ws_size >= full_bytes) {
    float* Y = (float*)d_ws;
    dim3 grid(T_LEN * B_SZ / BM, D_SZ / BN);
    gemm8x8_kernel<<<grid, 256, 0, stream>>>(x, W, b, Y);
    scan_chunk_kernel<<<dim3(BD / 64, CHK), 64, 0, stream>>>(Y, out);
  } else {
    // Chunked fallback; Tc a power-of-two divisor of T_LEN (>=4) so chunk
    // rows are a multiple of BM=128.
    const size_t avail = ws_size > vbytes ? ws_size - vbytes : 0;
    int Tc = T_LEN;
    while (Tc > 4 && (size_t)Tc * BD * sizeof(float) > avail) Tc >>= 1;
    float* Y      = (float*)d_ws;
    float* vstate = (float*)((char*)d_ws + (size_t)Tc * BD * sizeof(float));

    int first = 1;
    for (int t0 = 0; t0 < T_LEN; t0 += Tc) {
      dim3 grid(Tc * B_SZ / BM, D_SZ / BN);
      gemm8x8_kernel<<<grid, 256, 0, stream>>>(x + (size_t)t0 * BD, W, b, Y);
      lif_fwd_kernel<<<BD / 64, 64, 0, stream>>>(Y, out + (size_t)t0 * BD, Tc,
                                                 vstate, first ? 0 : 1);
      first = 0;
    }
    first = 1;
    for (int t0 = T_LEN - Tc; t0 >= 0; t0 -= Tc) {
      dim3 grid(Tc * B_SZ / BM, D_SZ / BN);
      gemm8x8_kernel<<<grid, 256, 0, stream>>>(x + (size_t)t0 * BD, W, b, Y);
      lif_bwd_kernel<<<BD / 64, 64, 0, stream>>>(Y, out + (size_t)t0 * BD, Tc,
                                                 vstate, first ? 0 : 1);
      first = 0;
    }
  }
}

// Round 6
// 644.119 us; speedup vs baseline: 1.1817x; 1.1817x over previous
//
#include <hip/hip_runtime.h>
#include <cstddef>
#include <cstdint>

// Shapes fixed by reference setup_inputs():
#define T_LEN 2048
#define B_SZ  32
#define D_SZ  512
#define BD    (B_SZ * D_SZ)   // 16384

// ---------------------------------------------------------------------------
// GEMM (R5, measured 464 us, VALUBusy 84%, VGPR 80 — UNCHANGED this round):
// per output element, single sequential fmaf chain over k=0..511 ascending,
// then + bias[e]. Chain order (k0 asc, kq asc, x/y/z/w asc) bit-exact vs ref.
//  - A and B staged via global_load_lds into linear [2][128*16] tiles (32 KB).
//    No ds_write, no prefetch registers.
//  - XOR quad swizzles (linear dest + inverse-swizzled SOURCE + same XOR on
//    READ): A: p=q^(row&3) -> 0-way read conflict; B: p=q^((row>>1)&3) ->
//    2-way (free).
//  - ONE barrier per 16-wide K-chunk; glds for chunk k+1 issued before
//    compute of chunk k, drained by the barrier.
//  - Bijective XCD swizzle (FETCH 272->85 MB proven).
// NOTE: SQ_LDS_BANK_CONFLICT ~3.3e7 here is a glds wide-write artifact
// (identical across R3/R5 with different read layouts) — not a real conflict.
// NOTE: plain __launch_bounds__(256). (256,4) clamped to 64 VGPR and
// spilled acc[8][8] (8.5x regression). Do not re-add.
// ---------------------------------------------------------------------------
#define BM   128
#define BN   128

typedef const __attribute__((address_space(1))) uint32_t* gas1_t;
typedef __attribute__((address_space(3))) uint32_t* las3_t;

__global__ __launch_bounds__(256) void gemm8x8_kernel(
    const float* __restrict__ A,     // [rows, 512]
    const float* __restrict__ W,     // [512, 512]
    const float* __restrict__ bias,  // [512]
    float* __restrict__ Y)           // [rows, 512]
{
#pragma clang fp contract(off)
  __shared__ float As[2][BM * 16];     // 8 KB per buf, linear, glds dest
  __shared__ float Bs[2][BN * 16];     // 8 KB per buf, linear, glds dest

  const int tid = threadIdx.x;
  const int tx  = tid & 15;          // n-lane: n = tx + 16*j
  const int ty  = tid >> 4;          // m-lane: m = ty + 16*i (0..15)
  const int cA  = ty & 3;            // A read-side quad XOR
  const int cB  = (tx >> 1) & 3;     // B read-side quad XOR

  // Bijective XCD swizzle (n-fast).
  const int nwg  = (int)(gridDim.x * gridDim.y);
  const int orig = (int)(blockIdx.y * gridDim.x + blockIdx.x);
  const int q    = nwg >> 3, r = nwg & 7;
  const int xcd  = orig & 7, loc = orig >> 3;
  const int tix  = (xcd < r ? xcd * (q + 1) : r * (q + 1) + (xcd - r) * q) + loc;
  const int m0   = (tix >> 2) * BM;   // gridDim.y == 4 (D_SZ/BN)
  const int n0   = (tix & 3) * BN;

  // glds staging: wave w stages A segs {2w,2w+1} and B segs {2w,2w+1};
  // lane l lands at seg_base + l*16B. Lane fetches the logical quad that
  // belongs at its phys slot: A: (l&3)^(rloc&3); B: (l&3)^((rloc>>1)&3).
  const int lane  = tid & 63;
  const int wid   = tid >> 6;                      // 0..3
  const int rloc  = lane >> 2;
  const int qA4   = (((lane & 3) ^ (rloc & 3)) << 2);
  const int qB4   = (((lane & 3) ^ ((rloc >> 1) & 3)) << 2);
  const int s0    = 2 * wid, s1 = 2 * wid + 1;
  const int oS0   = s0 * 256, oS1 = s1 * 256;      // LDS float offsets
  const float* gA0 = A + (size_t)(m0 + s0 * 16 + rloc) * D_SZ + qA4;
  const float* gA1 = A + (size_t)(m0 + s1 * 16 + rloc) * D_SZ + qA4;
  const float* gB0 = W + (size_t)(n0 + s0 * 16 + rloc) * D_SZ + qB4;
  const float* gB1 = W + (size_t)(n0 + s1 * 16 + rloc) * D_SZ + qB4;

#define STAGE(BUF, KOFF)                                                      \
  do {                                                                        \
    __builtin_amdgcn_global_load_lds((gas1_t)(const void*)(gA0 + (KOFF)),     \
                                     (las3_t)(void*)(&As[BUF][oS0]), 16, 0, 0);\
    __builtin_amdgcn_global_load_lds((gas1_t)(const void*)(gA1 + (KOFF)),     \
                                     (las3_t)(void*)(&As[BUF][oS1]), 16, 0, 0);\
    __builtin_amdgcn_global_load_lds((gas1_t)(const void*)(gB0 + (KOFF)),     \
                                     (las3_t)(void*)(&Bs[BUF][oS0]), 16, 0, 0);\
    __builtin_amdgcn_global_load_lds((gas1_t)(const void*)(gB1 + (KOFF)),     \
                                     (las3_t)(void*)(&Bs[BUF][oS1]), 16, 0, 0);\
  } while (0)

  float acc[8][8];
#pragma unroll
  for (int i = 0; i < 8; ++i)
#pragma unroll
    for (int j = 0; j < 8; ++j) acc[i][j] = 0.0f;

  STAGE(0, 0);
  __syncthreads();

#pragma unroll 1
  for (int kc = 0; kc < 32; ++kc) {
    const int cur = kc & 1;
    if (kc + 1 < 32) STAGE(cur ^ 1, (kc + 1) * 16);

    const float* asb = &As[cur][0];
    const float* bsb = &Bs[cur][0];
#pragma unroll
    for (int kq = 0; kq < 4; ++kq) {
      const int bq = ((kq ^ cB) & 3) << 2;   // phys quad holding logical kq
      const int aq = ((kq ^ cA) & 3) << 2;
      float4 bfr[8];
#pragma unroll
      for (int j = 0; j < 8; ++j)
        bfr[j] = *(const float4*)&bsb[(tx + 16 * j) * 16 + bq];
#pragma unroll
      for (int i = 0; i < 8; ++i) {
        const float4 a = *(const float4*)&asb[(ty + 16 * i) * 16 + aq];
#pragma unroll
        for (int j = 0; j < 8; ++j) {
          acc[i][j] = fmaf(a.x, bfr[j].x, acc[i][j]);
          acc[i][j] = fmaf(a.y, bfr[j].y, acc[i][j]);
          acc[i][j] = fmaf(a.z, bfr[j].z, acc[i][j]);
          acc[i][j] = fmaf(a.w, bfr[j].w, acc[i][j]);
        }
      }
    }
    __syncthreads();   // drains vmcnt: next buf landed; cur reads complete.
  }
#undef STAGE

#pragma unroll
  for (int i = 0; i < 8; ++i) {
    const int m = m0 + ty + 16 * i;
#pragma unroll
    for (int j = 0; j < 8; ++j) {
      const int n = n0 + tx + 16 * j;
      Y[(size_t)m * D_SZ + n] = acc[i][j] + bias[n];
    }
  }
}

// ---------------------------------------------------------------------------
// Chunked LIF scan with warm-up, writing out directly (R4 structure —
// rolled loops, compact code, 4096 waves, measured 170 us — with warm-up
// halved to 64 steps, proven bit-exact by R5's absmax=0).
// T split into CHK=16 chunks of CLEN=128. Per thread per direction: 64-step
// warm-up from v=0 over the neighbor chunk (residual influence 2^-64 << ulp;
// any spike hard-resets v to exact 0 -> bit-exact merge), then 128 real
// steps. Step math identical to verified scan.
// NOTE (R5 lesson): do NOT fully unroll this kernel into straight-line
// code (ca/cb 2-deep unrolled variant regressed 170->297 us; giant body).
// ---------------------------------------------------------------------------
#define CHK  16
#define CLEN 128

__global__ __launch_bounds__(64) void scan_chunk_kernel(
    const float* __restrict__ Y,
    float* __restrict__ out)
{
#pragma clang fp contract(off)
  const int idx = blockIdx.x * 64 + threadIdx.x;   // column in [0, BD)
  const int c   = blockIdx.y;                      // chunk
  const int t0  = c * CLEN;
  float creg[32];
  uint32_t sf0, sf1, sf2, sf3;
  float v;

#define LOAD32(TB)                                                            \
  _Pragma("unroll")                                                           \
  for (int j = 0; j < 32; ++j) creg[j] = Y[(size_t)((TB) + j) * BD + idx];

  // ---------------- forward ----------------
  v = 0.0f;
  if (c > 0) {                       // warm-up: 64 steps over tail of prev
#pragma unroll 1
    for (int g = 0; g < 2; ++g) {
      LOAD32(t0 - 64 + g * 32)
#pragma unroll
      for (int j = 0; j < 32; ++j) {
        v = v + (creg[j] - v) * 0.5f;
        const bool s = (v - 1.0f) >= 0.0f;
        v = s ? 0.0f : v;
      }
    }
  }
#define FGRP(SF, G)                                                           \
  {                                                                           \
    LOAD32(t0 + (G) * 32)                                                     \
    uint32_t w = 0;                                                           \
    _Pragma("unroll")                                                         \
    for (int j = 0; j < 32; ++j) {                                            \
      v = v + (creg[j] - v) * 0.5f;                                           \
      const bool s = (v - 1.0f) >= 0.0f;                                      \
      w |= (uint32_t)s << j;                                                  \
      v = s ? 0.0f : v;                                                       \
    }                                                                         \
    SF = w;                                                                   \
  }
  FGRP(sf0, 0) FGRP(sf1, 1) FGRP(sf2, 2) FGRP(sf3, 3)

  // ---------------- backward (t descending) ----------------
  v = 0.0f;
  if (c < CHK - 1) {                 // warm-up: 64 steps over head of next
#pragma unroll 1
    for (int g = 1; g >= 0; --g) {
      LOAD32(t0 + CLEN + g * 32)
#pragma unroll
      for (int j = 31; j >= 0; --j) {
        v = v + (creg[j] - v) * 0.5f;
        const bool s = (v - 1.0f) >= 0.0f;
        v = s ? 0.0f : v;
      }
    }
  }
  uint32_t sb0, sb1, sb2, sb3;
#define BGRP(SB, G)                                                           \
  {                                                                           \
    LOAD32(t0 + (G) * 32)                                                     \
    uint32_t w = 0;                                                           \
    _Pragma("unroll")                                                         \
    for (int j = 31; j >= 0; --j) {                                           \
      v = v + (creg[j] - v) * 0.5f;                                           \
      const bool s = (v - 1.0f) >= 0.0f;                                      \
      w |= (uint32_t)s << j;                                                  \
      v = s ? 0.0f : v;                                                       \
    }                                                                         \
    SB = w;                                                                   \
  }
  BGRP(sb3, 3) BGRP(sb2, 2) BGRP(sb1, 1) BGRP(sb0, 0)

  // ---------------- write ----------------
#define WGRP(SF, SB, G)                                                       \
  _Pragma("unroll")                                                           \
  for (int j = 0; j < 32; ++j)                                                \
    out[(size_t)(t0 + (G) * 32 + j) * BD + idx] =                             \
        (float)(((SF >> j) & 1u) + ((SB >> j) & 1u));
  WGRP(sf0, sb0, 0) WGRP(sf1, sb1, 1) WGRP(sf2, sb2, 2) WGRP(sf3, sb3, 3)

#undef LOAD32
#undef FGRP
#undef BGRP
#undef WGRP
}

// ---------------------------------------------------------------------------
// Fallback scans (used only if ws is too small for full Y).
// ---------------------------------------------------------------------------
__global__ __launch_bounds__(64) void lif_fwd_kernel(
    const float* __restrict__ Y, float* __restrict__ out,
    int tlen, float* __restrict__ vstate, int carry)
{
#pragma clang fp contract(off)
  const int idx = blockIdx.x * 64 + threadIdx.x;
  float v = carry ? vstate[idx] : 0.0f;
#pragma unroll 16
  for (int t = 0; t < tlen; ++t) {
    const float c = Y[(size_t)t * BD + idx];
    v = v + (c - v) * 0.5f;
    const bool s = (v - 1.0f) >= 0.0f;
    out[(size_t)t * BD + idx] = s ? 1.0f : 0.0f;
    v = s ? 0.0f : v;
  }
  vstate[idx] = v;
}

__global__ __launch_bounds__(64) void lif_bwd_kernel(
    const float* __restrict__ Y, float* __restrict__ out,
    int tlen, float* __restrict__ vstate, int carry)
{
#pragma clang fp contract(off)
  const int idx = blockIdx.x * 64 + threadIdx.x;
  float v = carry ? vstate[idx] : 0.0f;
#pragma unroll 16
  for (int tt = 0; tt < tlen; ++tt) {
    const size_t t = (size_t)(tlen - 1 - tt);
    const float c = Y[t * BD + idx];
    v = v + (c - v) * 0.5f;
    const bool s = (v - 1.0f) >= 0.0f;
    out[t * BD + idx] += s ? 1.0f : 0.0f;
    v = s ? 0.0f : v;
  }
  vstate[idx] = v;
}

// ---------------------------------------------------------------------------
extern "C" void kernel_launch(void* const* d_in, const int* in_sizes, int n_in,
                              void* d_out, int out_size, void* d_ws, size_t ws_size,
                              hipStream_t stream)
{
  const float* x = (const float*)d_in[0];   // [T, B, D]
  const float* W = (const float*)d_in[1];   // [D, D]
  const float* b = (const float*)d_in[2];   // [D]
  float* out = (float*)d_out;               // [T, B, D]

  const size_t full_bytes = (size_t)T_LEN * BD * sizeof(float);     // 134 MB
  const size_t vbytes     = (size_t)BD * sizeof(float);

  if (ws_size >= full_bytes) {
    float* Y = (float*)d_ws;
    dim3 grid(T_LEN * B_SZ / BM, D_SZ / BN);
    gemm8x8_kernel<<<grid, 256, 0, stream>>>(x, W, b, Y);
    scan_chunk_kernel<<<dim3(BD / 64, CHK), 64, 0, stream>>>(Y, out);
  } else {
    // Chunked fallback; Tc a power-of-two divisor of T_LEN (>=4) so chunk
    // rows are a multiple of BM=128.
    const size_t avail = ws_size > vbytes ? ws_size - vbytes : 0;
    int Tc = T_LEN;
    while (Tc > 4 && (size_t)Tc * BD * sizeof(float) > avail) Tc >>= 1;
    float* Y      = (float*)d_ws;
    float* vstate = (float*)((char*)d_ws + (size_t)Tc * BD * sizeof(float));

    int first = 1;
    for (int t0 = 0; t0 < T_LEN; t0 += Tc) {
      dim3 grid(Tc * B_SZ / BM, D_SZ / BN);
      gemm8x8_kernel<<<grid, 256, 0, stream>>>(x + (size_t)t0 * BD, W, b, Y);
      lif_fwd_kernel<<<BD / 64, 64, 0, stream>>>(Y, out + (size_t)t0 * BD, Tc,
                                                 vstate, first ? 0 : 1);
      first = 0;
    }
    first = 1;
    for (int t0 = T_LEN - Tc; t0 >= 0; t0 -= Tc) {
      dim3 grid(Tc * B_SZ / BM, D_SZ / BN);
      gemm8x8_kernel<<<grid, 256, 0, stream>>>(x + (size_t)t0 * BD, W, b, Y);
      lif_bwd_kernel<<<BD / 64, 64, 0, stream>>>(Y, out + (size_t)t0 * BD, Tc,
                                                 vstate, first ? 0 : 1);
      first = 0;
    }
  }
}